// Round 25
// baseline (38.540 us; speedup 1.0000x reference)
//
#include <hip/hip_runtime.h>
#include <stdint.h>

#define NB 4
#define NT 2048
#define NC 1024
#define NH 64
#define NM (NB*NT)

typedef unsigned short u16;
typedef unsigned int u32;
typedef __bf16 bf16_t;
typedef float f32x4 __attribute__((ext_vector_type(4)));
typedef bf16_t bf16x8 __attribute__((ext_vector_type(8)));
typedef u16 u16x8 __attribute__((ext_vector_type(8)));
typedef u16 u16x4 __attribute__((ext_vector_type(4)));

__device__ __forceinline__ u16 f2b(float f) {
  return __builtin_bit_cast(u16, (bf16_t)f);
}

// async global->LDS 16B: LDS dest = WAVE-UNIFORM base + lane*16 (m104);
// per-lane swizzle folded into the GLOBAL source address (m173).
__device__ __forceinline__ void gl16(const void* g, void* l) {
  __builtin_amdgcn_global_load_lds(
      (const __attribute__((address_space(1))) u32*)g,
      (__attribute__((address_space(3))) u32*)l, 16, 0, 0);
}

// ---------------- Wq/Wk/Wv [1024][64] f32 -> WT [3][64][1024] bf16 (transposed)
__global__ __launch_bounds__(256) void wt_kernel(const float* __restrict__ Wq,
                                                 const float* __restrict__ Wk,
                                                 const float* __restrict__ Wv,
                                                 u16* __restrict__ wt) {
  __shared__ float t[64][65];
  const int m = blockIdx.x >> 4;
  const int kt = blockIdx.x & 15;
  const int k0 = kt * 64;
  const float* W = (m == 0) ? Wq : (m == 1) ? Wk : Wv;
  {
    const int r = threadIdx.x >> 2, c4 = threadIdx.x & 3;
    #pragma unroll
    for (int j = 0; j < 4; ++j) {
      const float4 f = *(const float4*)(W + (size_t)(k0 + r) * NH + c4 * 16 + j * 4);
      t[r][c4 * 16 + j * 4 + 0] = f.x;
      t[r][c4 * 16 + j * 4 + 1] = f.y;
      t[r][c4 * 16 + j * 4 + 2] = f.z;
      t[r][c4 * 16 + j * 4 + 3] = f.w;
    }
  }
  __syncthreads();
  const int n = threadIdx.x >> 2, kc = threadIdx.x & 3;
  u16x8 a, b;
  #pragma unroll
  for (int j = 0; j < 8; ++j) a[j] = f2b(t[kc * 16 + j][n]);
  #pragma unroll
  for (int j = 0; j < 8; ++j) b[j] = f2b(t[kc * 16 + 8 + j][n]);
  u16* dst = wt + ((size_t)(m * 64 + n)) * NC + k0 + kc * 16;
  *(u16x8*)dst = a;
  *(u16x8*)(dst + 8) = b;
}

// ---------------- proj-v10 (r24 — byte-identical, best known)
__global__ __launch_bounds__(512) void proj_kernel(const float* __restrict__ x,
                                                   const u16* __restrict__ wt,
                                                   u16* __restrict__ qo,
                                                   u16* __restrict__ ko,
                                                   u16* __restrict__ vto) {
  __shared__ float fA[2][32 * 64];
  __shared__ u16 sB[2][64 * 64];
  const int tid = threadIdx.x;
  const int lane = tid & 63;
  const int wv = tid >> 6;
  const int rt = wv & 1;
  const int w = wv >> 1;
  const int g = lane >> 4;
  const int li = lane & 15;
  const int row0 = blockIdx.x * 32;
  const int m = blockIdx.y;
  const int wbase16 = (tid & 0x1C0) * 16;
  const u16* wslice = wt + (size_t)m * 64 * NC;

  const f32x4 zero = {0.f, 0.f, 0.f, 0.f};
  f32x4 acc = zero;

  const int ar = tid >> 4, ac = tid & 15;
  const int bn = tid >> 3, bc = tid & 7;
  const float* asrc = x + (size_t)(row0 + ar) * NC + ((ac ^ (ar & 7)) * 4);
  const u16* bsrc = wslice + (size_t)bn * NC + ((bc ^ (bn & 7)) * 8);

  auto stage = [&](int kt, int nxt) {
    const int k0 = kt * 64;
    gl16(asrc + k0, (char*)fA[nxt] + wbase16 + (lane << 4));
    gl16(bsrc + k0, (char*)sB[nxt] + wbase16 + (lane << 4));
  };

  stage(0, 0);
  __syncthreads();

  for (int kt = 0; kt < 16; ++kt) {
    const int cur = kt & 1;
    if (kt < 15) stage(kt + 1, cur ^ 1);
    #pragma unroll
    for (int ks = 0; ks < 2; ++ks) {
      const int n = w * 16 + li;
      const bf16x8 b = *(const bf16x8*)&sB[cur][n * 64 + (((ks * 4 + g) ^ (n & 7)) * 8)];
      const int r = rt * 16 + li;
      const int c0 = ks * 8 + g * 2;
      const f32x4 a0 = *(const f32x4*)&fA[cur][r * 64 + ((c0 ^ (r & 7)) * 4)];
      const f32x4 a1 = *(const f32x4*)&fA[cur][r * 64 + (((c0 + 1) ^ (r & 7)) * 4)];
      bf16x8 a;
      a[0]=(bf16_t)a0.x; a[1]=(bf16_t)a0.y; a[2]=(bf16_t)a0.z; a[3]=(bf16_t)a0.w;
      a[4]=(bf16_t)a1.x; a[5]=(bf16_t)a1.y; a[6]=(bf16_t)a1.z; a[7]=(bf16_t)a1.w;
      acc = __builtin_amdgcn_mfma_f32_16x16x32_bf16(a, b, acc, 0, 0, 0);
    }
    __syncthreads();
  }

  const int rr0 = row0 + rt * 16 + g * 4;
  if (m == 0) {
    #pragma unroll
    for (int i = 0; i < 4; ++i)
      qo[(size_t)(rr0 + i) * NH + w * 16 + li] = f2b(acc[i]);
  } else if (m == 1) {
    #pragma unroll
    for (int i = 0; i < 4; ++i)
      ko[(size_t)(rr0 + i) * NH + w * 16 + li] = f2b(acc[i]);
  } else {
    u16x4 pv;
    #pragma unroll
    for (int i = 0; i < 4; ++i) pv[i] = f2b(acc[i]);
    const int hs = w * 16 + li;
    const int bidx = rr0 >> 11;
    const int tt = rr0 & 2047;
    const int tile = tt >> 6, off = tt & 63;
    *(u16x4*)&vto[(((size_t)(bidx * 32 + tile) * 64) + hs) * 64 + off] = pv;
  }
}

// ---------------- attention v5: 16 kv-splits x 1024 thr; K gl16 dbuf per wave,
// V via register loads (r18-proven); 16 waves/CU (vs 8); in-block 16-way merge.
struct AttnGrp {
  union {
    u16 K[2][32 * 64];                                    // 8 KB
    struct { float mo[2][16][64]; float ml[2][16]; } mg;  // merge alias
  } u;
};

__global__ __launch_bounds__(1024) void attn_kernel(const u16* __restrict__ qg,
                                                    const u16* __restrict__ kg,
                                                    const u16* __restrict__ vtg,
                                                    float* __restrict__ out) {
  __shared__ AttnGrp grp[16];         // ~131 KB
  __shared__ u16 sP[16][16 * 32];     // 16 KB
  const int tid = threadIdx.x;
  const int lane = tid & 63;
  const int s = tid >> 6;             // wave 0..15 = kv split
  const int g = lane >> 4;
  const int li = lane & 15;
  const int jA = blockIdx.x & 63;
  const int bb = blockIdx.x >> 6;
  const int jB = 127 - jA;
  const size_t bt0 = (size_t)bb * NT;
  const int q0A = jA * 16, q0B = jB * 16;
  const int n1 = (jA >> 1) + 1;       // A's kv tiles; union = 65 always

  bf16x8 aqA[2], aqB[2];
  #pragma unroll
  for (int ks = 0; ks < 2; ++ks) {
    aqA[ks] = *(const bf16x8*)(qg + (bt0 + q0A + li) * NH + ks * 32 + g * 8);
    aqB[ks] = *(const bf16x8*)(qg + (bt0 + q0B + li) * NH + ks * 32 + g * 8);
  }

  const f32x4 zero = {0.f, 0.f, 0.f, 0.f};
  f32x4 oA[4], oB[4];
  float lA[4], lB[4];
  #pragma unroll
  for (int i = 0; i < 4; ++i) { oA[i] = zero; oB[i] = zero; lA[i] = 0.f; lB[i] = 0.f; }

  // stage K tile for virtual index v into wave-private buf b (exactly 4 gl16)
  auto stageK = [&](int v, int b) {
    const int kvt = (v < n1) ? v : v - n1;
    const size_t kbase = bt0 + (size_t)kvt * 32;
    #pragma unroll
    for (int jj = 0; jj < 4; ++jj) {
      const int idx = jj * 64 + lane;
      const int n = idx >> 3, c = idx & 7;
      gl16(kg + (kbase + n) * NH + ((c ^ (n & 7)) * 8),
           (char*)grp[s].u.K[b] + jj * 1024);
    }
  };

  auto computeT = [&](const bf16x8 (&aq)[2], f32x4 (&o)[4], float (&ls)[4],
                      int q0, int kv0, int b, const bf16x8 (&vf)[4]) {
    f32x4 sc2[2] = {zero, zero};
    #pragma unroll
    for (int ks = 0; ks < 2; ++ks) {
      #pragma unroll
      for (int fn = 0; fn < 2; ++fn) {
        const int n = fn * 16 + li;
        const bf16x8 bk = *(const bf16x8*)&grp[s].u.K[b][n * 64 + (((ks * 4 + g) ^ (n & 7)) * 8)];
        sc2[fn] = __builtin_amdgcn_mfma_f32_16x16x32_bf16(aq[ks], bk, sc2[fn], 0, 0, 0);
      }
    }
    const bool needmask = (kv0 + 31 > q0);
    #pragma unroll
    for (int fn = 0; fn < 2; ++fn) {
      #pragma unroll
      for (int i = 0; i < 4; ++i) {
        const int q = g * 4 + i;
        float v = sc2[fn][i] * 0.125f;
        if (needmask && (kv0 + fn * 16 + li > q0 + q)) v = -1e30f;
        const float e = __expf(v);
        ls[i] += e;
        const int kc = fn * 2 + (li >> 3);
        sP[s][q * 32 + ((kc ^ (q & 3) ^ ((q >> 2) & 3)) * 8) + (li & 7)] = f2b(e);
      }
    }
    const bf16x8 pa = *(const bf16x8*)&sP[s][li * 32 + ((g ^ (li & 3) ^ ((li >> 2) & 3)) * 8)];
    #pragma unroll
    for (int fn = 0; fn < 4; ++fn)
      o[fn] = __builtin_amdgcn_mfma_f32_16x16x32_bf16(pa, vf[fn], o[fn], 0, 0, 0);
  };

  stageK(s, 0);
  int k = 0;
  for (int v = s; v < 65; v += 16, ++k) {
    const int kvt = (v < n1) ? v : v - n1;
    // V fragments: 4 plain vector loads (before next stage; compiler's pre-use
    // wait drains them without touching the gl16 prefetch)
    bf16x8 vf[4];
    const size_t vrow = ((size_t)(bb * 32 + (kvt >> 1))) * 64;
    const int hoff = (kvt & 1) * 32;
    #pragma unroll
    for (int fn = 0; fn < 4; ++fn)
      vf[fn] = *(const bf16x8*)(vtg + (vrow + fn * 16 + li) * 64 + hoff + g * 8);

    if (v + 16 < 65) {
      stageK(v + 16, (k + 1) & 1);
      // outstanding: gl16(v).4 | vf.4 | gl16(v+16).4 -> drain gl16(v)
      asm volatile("s_waitcnt vmcnt(8)" ::: "memory");
    } else {
      asm volatile("s_waitcnt vmcnt(4)" ::: "memory");   // drain gl16(v), keep vf
    }
    const int b = k & 1;
    if (v < n1) computeT(aqA, oA, lA, q0A, kvt * 32, b, vf);
    else        computeT(aqB, oB, lB, q0B, kvt * 32, b, vf);
  }

  // row-reduce l within 16-lane groups
  #pragma unroll
  for (int i = 0; i < 4; ++i) {
    float a = lA[i], c = lB[i];
    a += __shfl_xor(a, 1); c += __shfl_xor(c, 1);
    a += __shfl_xor(a, 2); c += __shfl_xor(c, 2);
    a += __shfl_xor(a, 4); c += __shfl_xor(c, 4);
    a += __shfl_xor(a, 8); c += __shfl_xor(c, 8);
    lA[i] = a; lB[i] = c;
  }

  // write partials to this wave's LDS region (wave-private alias of K bufs)
  #pragma unroll
  for (int fn = 0; fn < 4; ++fn) {
    #pragma unroll
    for (int i = 0; i < 4; ++i) {
      grp[s].u.mg.mo[0][g * 4 + i][fn * 16 + li] = oA[fn][i];
      grp[s].u.mg.mo[1][g * 4 + i][fn * 16 + li] = oB[fn][i];
    }
  }
  if (li == 0) {
    #pragma unroll
    for (int i = 0; i < 4; ++i) {
      grp[s].u.mg.ml[0][g * 4 + i] = lA[i];
      grp[s].u.mg.ml[1][g * 4 + i] = lB[i];
    }
  }
  __syncthreads();

  // combine 16 splits, write out (2048 f32 per block, 2 per thread)
  {
    const int base = tid * 2;
    const int tile = base >> 10;
    const int r = (base >> 6) & 15;
    const int c0 = base & 63;
    float L = 0.f;
    float a0 = 0.f, a1 = 0.f;
    #pragma unroll
    for (int s16 = 0; s16 < 16; ++s16) {
      L += grp[s16].u.mg.ml[tile][r];
      a0 += grp[s16].u.mg.mo[tile][r][c0];
      a1 += grp[s16].u.mg.mo[tile][r][c0 + 1];
    }
    const int row = (tile ? q0B : q0A) + r;
    const float inv = 1.f / L;
    out[(bt0 + row) * NH + c0] = a0 * inv;
    out[(bt0 + row) * NH + c0 + 1] = a1 * inv;
  }
}

extern "C" void kernel_launch(void* const* d_in, const int* in_sizes, int n_in,
                              void* d_out, int out_size, void* d_ws, size_t ws_size,
                              hipStream_t stream) {
  (void)in_sizes; (void)n_in; (void)out_size; (void)ws_size;
  const float* x  = (const float*)d_in[0];
  const float* Wq = (const float*)d_in[1];
  const float* Wk = (const float*)d_in[2];
  const float* Wv = (const float*)d_in[3];
  float* out = (float*)d_out;
  char* ws = (char*)d_ws;
  u16* qb  = (u16*)(ws);                    // 1 MB   : q bf16 [8192][64]
  u16* kb  = (u16*)(ws + (1u << 20));       // 1 MB   : k bf16 [8192][64]
  u16* vtb = (u16*)(ws + (2u << 20));       // 1 MB   : v^T bf16 tiled [4][32][64][64]
  u16* wtb = (u16*)(ws + (3u << 20));       // 384 KB : WT bf16 [3][64][1024]
  hipLaunchKernelGGL(wt_kernel,   dim3(48),     dim3(256),  0, stream, Wq, Wk, Wv, wtb);
  hipLaunchKernelGGL(proj_kernel, dim3(256, 3), dim3(512),  0, stream, x, wtb, qb, kb, vtb);
  hipLaunchKernelGGL(attn_kernel, dim3(256),    dim3(1024), 0, stream, qb, kb, vtb, out);
}

// Round 26
// 35.408 us; speedup vs baseline: 1.0885x; 1.0885x over previous
//
#include <hip/hip_runtime.h>
#include <stdint.h>

#define NB 4
#define NT 2048
#define NC 1024
#define NH 64
#define NM (NB*NT)

typedef unsigned short u16;
typedef unsigned int u32;
typedef __bf16 bf16_t;
typedef float f32x4 __attribute__((ext_vector_type(4)));
typedef bf16_t bf16x8 __attribute__((ext_vector_type(8)));
typedef u16 u16x8 __attribute__((ext_vector_type(8)));
typedef u16 u16x4 __attribute__((ext_vector_type(4)));

__device__ __forceinline__ u16 f2b(float f) {
  return __builtin_bit_cast(u16, (bf16_t)f);
}

// async global->LDS 16B: LDS dest = WAVE-UNIFORM base + lane*16 (m104);
// per-lane swizzle folded into the GLOBAL source address (m173).
__device__ __forceinline__ void gl16(const void* g, void* l) {
  __builtin_amdgcn_global_load_lds(
      (const __attribute__((address_space(1))) u32*)g,
      (__attribute__((address_space(3))) u32*)l, 16, 0, 0);
}

// ---------------- Wq/Wk/Wv [1024][64] f32 -> WT [3][64][1024] bf16 (transposed)
__global__ __launch_bounds__(256) void wt_kernel(const float* __restrict__ Wq,
                                                 const float* __restrict__ Wk,
                                                 const float* __restrict__ Wv,
                                                 u16* __restrict__ wt) {
  __shared__ float t[64][65];
  const int m = blockIdx.x >> 4;
  const int kt = blockIdx.x & 15;
  const int k0 = kt * 64;
  const float* W = (m == 0) ? Wq : (m == 1) ? Wk : Wv;
  {
    const int r = threadIdx.x >> 2, c4 = threadIdx.x & 3;
    #pragma unroll
    for (int j = 0; j < 4; ++j) {
      const float4 f = *(const float4*)(W + (size_t)(k0 + r) * NH + c4 * 16 + j * 4);
      t[r][c4 * 16 + j * 4 + 0] = f.x;
      t[r][c4 * 16 + j * 4 + 1] = f.y;
      t[r][c4 * 16 + j * 4 + 2] = f.z;
      t[r][c4 * 16 + j * 4 + 3] = f.w;
    }
  }
  __syncthreads();
  const int n = threadIdx.x >> 2, kc = threadIdx.x & 3;
  u16x8 a, b;
  #pragma unroll
  for (int j = 0; j < 8; ++j) a[j] = f2b(t[kc * 16 + j][n]);
  #pragma unroll
  for (int j = 0; j < 8; ++j) b[j] = f2b(t[kc * 16 + 8 + j][n]);
  u16* dst = wt + ((size_t)(m * 64 + n)) * NC + k0 + kc * 16;
  *(u16x8*)dst = a;
  *(u16x8*)(dst + 8) = b;
}

// ---------------- proj-v10 (r24 — best known): 512 thr, 8 waves, 32KB LDS,
// thread-capped occupancy 4 blocks/CU x 8 waves = 32 waves/CU.
__global__ __launch_bounds__(512) void proj_kernel(const float* __restrict__ x,
                                                   const u16* __restrict__ wt,
                                                   u16* __restrict__ qo,
                                                   u16* __restrict__ ko,
                                                   u16* __restrict__ vto) {
  __shared__ float fA[2][32 * 64];
  __shared__ u16 sB[2][64 * 64];
  const int tid = threadIdx.x;
  const int lane = tid & 63;
  const int wv = tid >> 6;
  const int rt = wv & 1;
  const int w = wv >> 1;
  const int g = lane >> 4;
  const int li = lane & 15;
  const int row0 = blockIdx.x * 32;
  const int m = blockIdx.y;
  const int wbase16 = (tid & 0x1C0) * 16;
  const u16* wslice = wt + (size_t)m * 64 * NC;

  const f32x4 zero = {0.f, 0.f, 0.f, 0.f};
  f32x4 acc = zero;

  const int ar = tid >> 4, ac = tid & 15;
  const int bn = tid >> 3, bc = tid & 7;
  const float* asrc = x + (size_t)(row0 + ar) * NC + ((ac ^ (ar & 7)) * 4);
  const u16* bsrc = wslice + (size_t)bn * NC + ((bc ^ (bn & 7)) * 8);

  auto stage = [&](int kt, int nxt) {
    const int k0 = kt * 64;
    gl16(asrc + k0, (char*)fA[nxt] + wbase16 + (lane << 4));
    gl16(bsrc + k0, (char*)sB[nxt] + wbase16 + (lane << 4));
  };

  stage(0, 0);
  __syncthreads();

  for (int kt = 0; kt < 16; ++kt) {
    const int cur = kt & 1;
    if (kt < 15) stage(kt + 1, cur ^ 1);
    #pragma unroll
    for (int ks = 0; ks < 2; ++ks) {
      const int n = w * 16 + li;
      const bf16x8 b = *(const bf16x8*)&sB[cur][n * 64 + (((ks * 4 + g) ^ (n & 7)) * 8)];
      const int r = rt * 16 + li;
      const int c0 = ks * 8 + g * 2;
      const f32x4 a0 = *(const f32x4*)&fA[cur][r * 64 + ((c0 ^ (r & 7)) * 4)];
      const f32x4 a1 = *(const f32x4*)&fA[cur][r * 64 + (((c0 + 1) ^ (r & 7)) * 4)];
      bf16x8 a;
      a[0]=(bf16_t)a0.x; a[1]=(bf16_t)a0.y; a[2]=(bf16_t)a0.z; a[3]=(bf16_t)a0.w;
      a[4]=(bf16_t)a1.x; a[5]=(bf16_t)a1.y; a[6]=(bf16_t)a1.z; a[7]=(bf16_t)a1.w;
      acc = __builtin_amdgcn_mfma_f32_16x16x32_bf16(a, b, acc, 0, 0, 0);
    }
    __syncthreads();
  }

  const int rr0 = row0 + rt * 16 + g * 4;
  if (m == 0) {
    #pragma unroll
    for (int i = 0; i < 4; ++i)
      qo[(size_t)(rr0 + i) * NH + w * 16 + li] = f2b(acc[i]);
  } else if (m == 1) {
    #pragma unroll
    for (int i = 0; i < 4; ++i)
      ko[(size_t)(rr0 + i) * NH + w * 16 + li] = f2b(acc[i]);
  } else {
    u16x4 pv;
    #pragma unroll
    for (int i = 0; i < 4; ++i) pv[i] = f2b(acc[i]);
    const int hs = w * 16 + li;
    const int bidx = rr0 >> 11;
    const int tt = rr0 & 2047;
    const int tile = tt >> 6, off = tt & 63;
    *(u16x4*)&vto[(((size_t)(bidx * 32 + tile) * 64) + hs) * 64 + off] = pv;
  }
}

// ---------------- attention (r13 — byte-identical, best attn config)
struct AttnGrp {
  union {
    struct { u16 K[2][32 * 64]; u16 V[2][64 * 32]; } st;  // 16 KB
    struct { float mo[2][16][64]; float ml[2][16]; } mg;  // merge alias
  } u;
};

__global__ __launch_bounds__(512) void attn_kernel(const u16* __restrict__ qg,
                                                   const u16* __restrict__ kg,
                                                   const u16* __restrict__ vtg,
                                                   float* __restrict__ out) {
  __shared__ AttnGrp grp[8];
  __shared__ u16 sP[8][16 * 32];
  const int tid = threadIdx.x;
  const int lane = tid & 63;
  const int s = tid >> 6;
  const int g = lane >> 4;
  const int li = lane & 15;
  const int jA = blockIdx.x & 63;
  const int bb = blockIdx.x >> 6;
  const int jB = 127 - jA;
  const size_t bt0 = (size_t)bb * NT;
  const int q0A = jA * 16, q0B = jB * 16;
  const int n1 = (jA >> 1) + 1;

  bf16x8 aqA[2], aqB[2];
  #pragma unroll
  for (int ks = 0; ks < 2; ++ks) {
    aqA[ks] = *(const bf16x8*)(qg + (bt0 + q0A + li) * NH + ks * 32 + g * 8);
    aqB[ks] = *(const bf16x8*)(qg + (bt0 + q0B + li) * NH + ks * 32 + g * 8);
  }

  const f32x4 zero = {0.f, 0.f, 0.f, 0.f};
  f32x4 oA[4], oB[4];
  float lA[4], lB[4];
  #pragma unroll
  for (int i = 0; i < 4; ++i) { oA[i] = zero; oB[i] = zero; lA[i] = 0.f; lB[i] = 0.f; }

  auto stageKV = [&](int v, int b) {
    const int kvt = (v < n1) ? v : v - n1;
    const size_t kbase = bt0 + (size_t)kvt * 32;
    #pragma unroll
    for (int jj = 0; jj < 4; ++jj) {
      const int idx = jj * 64 + lane;
      const int n = idx >> 3, c = idx & 7;
      gl16(kg + (kbase + n) * NH + ((c ^ (n & 7)) * 8),
           (char*)grp[s].u.st.K[b] + jj * 1024);
    }
    const size_t vbase = ((size_t)(bb * 32 + (kvt >> 1))) * 64;
    const int hoff = (kvt & 1) * 32;
    #pragma unroll
    for (int jj = 0; jj < 4; ++jj) {
      const int idx = jj * 64 + lane;
      const int n = idx >> 2, c = idx & 3;
      gl16(vtg + (vbase + n) * 64 + hoff + ((c ^ (n & 3) ^ ((n >> 2) & 3)) * 8),
           (char*)grp[s].u.st.V[b] + jj * 1024);
    }
  };

  auto computeT = [&](const bf16x8 (&aq)[2], f32x4 (&o)[4], float (&ls)[4],
                      int q0, int kv0, int b) {
    f32x4 sc2[2] = {zero, zero};
    #pragma unroll
    for (int ks = 0; ks < 2; ++ks) {
      #pragma unroll
      for (int fn = 0; fn < 2; ++fn) {
        const int n = fn * 16 + li;
        const bf16x8 bk = *(const bf16x8*)&grp[s].u.st.K[b][n * 64 + (((ks * 4 + g) ^ (n & 7)) * 8)];
        sc2[fn] = __builtin_amdgcn_mfma_f32_16x16x32_bf16(aq[ks], bk, sc2[fn], 0, 0, 0);
      }
    }
    const bool needmask = (kv0 + 31 > q0);
    #pragma unroll
    for (int fn = 0; fn < 2; ++fn) {
      #pragma unroll
      for (int i = 0; i < 4; ++i) {
        const int q = g * 4 + i;
        float v = sc2[fn][i] * 0.125f;
        if (needmask && (kv0 + fn * 16 + li > q0 + q)) v = -1e30f;
        const float e = __expf(v);
        ls[i] += e;
        const int kc = fn * 2 + (li >> 3);
        sP[s][q * 32 + ((kc ^ (q & 3) ^ ((q >> 2) & 3)) * 8) + (li & 7)] = f2b(e);
      }
    }
    const bf16x8 pa = *(const bf16x8*)&sP[s][li * 32 + ((g ^ (li & 3) ^ ((li >> 2) & 3)) * 8)];
    #pragma unroll
    for (int fn = 0; fn < 4; ++fn) {
      const int n = fn * 16 + li;
      const bf16x8 bv = *(const bf16x8*)&grp[s].u.st.V[b][n * 32 + ((g ^ (n & 3) ^ ((n >> 2) & 3)) * 8)];
      o[fn] = __builtin_amdgcn_mfma_f32_16x16x32_bf16(pa, bv, o[fn], 0, 0, 0);
    }
  };

  const int nt = (64 - s) / 8 + 1;    // 65 tiles: split s gets 8 or 9
  int v = s;
  stageKV(v, 0);
  for (int k = 0; k < nt; ++k) {
    if (k + 1 < nt) {
      stageKV(v + 8, (k + 1) & 1);
      asm volatile("s_waitcnt vmcnt(8)" ::: "memory");
    } else {
      asm volatile("s_waitcnt vmcnt(0)" ::: "memory");
    }
    const int b = k & 1;
    if (v < n1) computeT(aqA, oA, lA, q0A, v * 32, b);
    else        computeT(aqB, oB, lB, q0B, (v - n1) * 32, b);
    v += 8;
  }

  #pragma unroll
  for (int i = 0; i < 4; ++i) {
    float a = lA[i], c = lB[i];
    a += __shfl_xor(a, 1); c += __shfl_xor(c, 1);
    a += __shfl_xor(a, 2); c += __shfl_xor(c, 2);
    a += __shfl_xor(a, 4); c += __shfl_xor(c, 4);
    a += __shfl_xor(a, 8); c += __shfl_xor(c, 8);
    lA[i] = a; lB[i] = c;
  }

  #pragma unroll
  for (int fn = 0; fn < 4; ++fn) {
    #pragma unroll
    for (int i = 0; i < 4; ++i) {
      grp[s].u.mg.mo[0][g * 4 + i][fn * 16 + li] = oA[fn][i];
      grp[s].u.mg.mo[1][g * 4 + i][fn * 16 + li] = oB[fn][i];
    }
  }
  if (li == 0) {
    #pragma unroll
    for (int i = 0; i < 4; ++i) {
      grp[s].u.mg.ml[0][g * 4 + i] = lA[i];
      grp[s].u.mg.ml[1][g * 4 + i] = lB[i];
    }
  }
  __syncthreads();

  {
    const int base = tid * 4;
    const int tile = base >> 10;
    const int r = (base >> 6) & 15;
    const int c0 = base & 63;
    float L = 0.f;
    f32x4 acc = zero;
    #pragma unroll
    for (int s8 = 0; s8 < 8; ++s8) {
      L += grp[s8].u.mg.ml[tile][r];
      acc += *(const f32x4*)&grp[s8].u.mg.mo[tile][r][c0];
    }
    const int row = (tile ? q0B : q0A) + r;
    const float inv = 1.f / L;
    acc *= inv;
    *(f32x4*)&out[(bt0 + row) * NH + c0] = acc;
  }
}

extern "C" void kernel_launch(void* const* d_in, const int* in_sizes, int n_in,
                              void* d_out, int out_size, void* d_ws, size_t ws_size,
                              hipStream_t stream) {
  (void)in_sizes; (void)n_in; (void)out_size; (void)ws_size;
  const float* x  = (const float*)d_in[0];
  const float* Wq = (const float*)d_in[1];
  const float* Wk = (const float*)d_in[2];
  const float* Wv = (const float*)d_in[3];
  float* out = (float*)d_out;
  char* ws = (char*)d_ws;
  u16* qb  = (u16*)(ws);                    // 1 MB   : q bf16 [8192][64]
  u16* kb  = (u16*)(ws + (1u << 20));       // 1 MB   : k bf16 [8192][64]
  u16* vtb = (u16*)(ws + (2u << 20));       // 1 MB   : v^T bf16 tiled [4][32][64][64]
  u16* wtb = (u16*)(ws + (3u << 20));       // 384 KB : WT bf16 [3][64][1024]
  hipLaunchKernelGGL(wt_kernel,   dim3(48),     dim3(256), 0, stream, Wq, Wk, Wv, wtb);
  hipLaunchKernelGGL(proj_kernel, dim3(256, 3), dim3(512), 0, stream, x, wtb, qb, kb, vtb);
  hipLaunchKernelGGL(attn_kernel, dim3(256),    dim3(512), 0, stream, qb, kb, vtb, out);
}